// Round 2
// baseline (160.545 us; speedup 1.0000x reference)
//
#include <hip/hip_runtime.h>
#include <cstdint>

typedef float v4f __attribute__((ext_vector_type(4)));

// 4 points per thread: all bulk streams become 16 B/lane (dwordx4) loads/stores.
// Per point: 1 sqrt + 4 reciprocal divides (was ~11 IEEE divides).
__global__ __launch_bounds__(256) void gs_project_kernel(
    const float* __restrict__ points,   // N*3
    const float* __restrict__ quats,    // N*4
    const float* __restrict__ scales,   // N*3
    const float* __restrict__ E,        // 16 (4x4 row-major extrinsic)
    const float* __restrict__ K,        // 12 (3x4 row-major intrinsic)
    float* __restrict__ out,            // [uv: 2N][z: N][cov: 4N]
    int n)
{
    const int t = blockIdx.x * blockDim.x + threadIdx.x;
    const long long i0 = (long long)t * 4;
    if (i0 >= n) return;

    // Wave-uniform broadcast loads (compiler -> s_load, stays in SGPRs).
    const float e00=E[0],  e01=E[1],  e02=E[2],  e03=E[3];
    const float e10=E[4],  e11=E[5],  e12=E[6],  e13=E[7];
    const float e20=E[8],  e21=E[9],  e22=E[10], e23=E[11];
    const float e30=E[12], e31=E[13], e32=E[14], e33=E[15];
    const float k00=K[0],  k01=K[1],  k02=K[2],  k03=K[3];
    const float k10=K[4],  k11=K[5],  k12=K[6],  k13=K[7];
    const float k20=K[8],  k21=K[9],  k22=K[10], k23=K[11];

    // Per-point math. qw..qz in reference order (w,x,y,z).
    auto project = [&](float px, float py, float pz,
                       float qw, float qx, float qy, float qz_,
                       float sx, float sy, float sz,
                       float& u, float& v, float& zc,
                       float& o00, float& o01, float& o10, float& o11)
    {
        const float qn  = sqrtf(qw*qw + qx*qx + qy*qy + qz_*qz_);
        const float qi  = 1.0f / qn;
        const float w = qw*qi, x = qx*qi, y = qy*qi, z = qz_*qi;

        const float r00 = 1.f - 2.f*(y*y + z*z);
        const float r01 = 2.f*(x*y - w*z);
        const float r02 = 2.f*(x*z + w*y);
        const float r10 = 2.f*(x*y + w*z);
        const float r11 = 1.f - 2.f*(x*x + z*z);
        const float r12 = 2.f*(y*z - w*x);
        const float r20 = 2.f*(x*z - w*y);
        const float r21 = 2.f*(y*z + w*x);
        const float r22 = 1.f - 2.f*(x*x + y*y);

        const float m00=r00*sx, m01=r01*sy, m02=r02*sz;
        const float m10=r10*sx, m11=r11*sy, m12=r12*sz;
        const float m20=r20*sx, m21=r21*sy, m22=r22*sz;

        const float c00 = m00*m00 + m01*m01 + m02*m02;
        const float c01 = m00*m10 + m01*m11 + m02*m12;
        const float c02 = m00*m20 + m01*m21 + m02*m22;
        const float c11 = m10*m10 + m11*m11 + m12*m12;
        const float c12 = m10*m20 + m11*m21 + m12*m22;
        const float c22 = m20*m20 + m21*m21 + m22*m22;

        const float camx = e00*px + e01*py + e02*pz + e03;
        const float camy = e10*px + e11*py + e12*pz + e13;
        const float camz = e20*px + e21*py + e22*pz + e23;
        const float camw = e30*px + e31*py + e32*pz + e33;
        const float iw = 1.0f / camw;
        const float cx = camx*iw, cy = camy*iw, cz = camz*iw;

        const float p0 = k00*cx + k01*cy + k02*cz + k03;
        const float p1 = k10*cx + k11*cy + k12*cz + k13;
        const float p2 = k20*cx + k21*cy + k22*cz + k23;
        const float ip2 = 1.0f / p2;
        u = p0*ip2; v = p1*ip2;
        zc = camz;                           // z_component is pre-divide cam[:,2]

        const float fx = k00, fy = k11;
        const float icz = 1.0f / cz;
        const float j00 = fx*icz;
        const float j02 = -fx*cx*icz*icz;
        const float j11 = fy*icz;
        const float j12 = -fy*cy*icz*icz;

        // T = J @ E[:3,:3]
        const float t00 = j00*e00 + j02*e20;
        const float t01 = j00*e01 + j02*e21;
        const float t02 = j00*e02 + j02*e22;
        const float t10 = j11*e10 + j12*e20;
        const float t11 = j11*e11 + j12*e21;
        const float t12 = j11*e12 + j12*e22;

        const float a00 = t00*c00 + t01*c01 + t02*c02;
        const float a01 = t00*c01 + t01*c11 + t02*c12;
        const float a02 = t00*c02 + t01*c12 + t02*c22;
        const float a10 = t10*c00 + t11*c01 + t12*c02;
        const float a11 = t10*c01 + t11*c11 + t12*c12;
        const float a12 = t10*c02 + t11*c12 + t12*c22;
        o00 = a00*t00 + a01*t01 + a02*t02;
        o01 = a00*t10 + a01*t11 + a02*t12;
        o10 = a10*t00 + a11*t01 + a12*t02;
        o11 = a10*t10 + a11*t11 + a12*t12;
    };

    if (((n & 3) == 0) && (i0 + 3 < n)) {
        // ---- fully vectorized path: every access is 16 B/lane ----
        const v4f* p4 = (const v4f*)points + 3*(size_t)t;
        const v4f* q4 = (const v4f*)quats  + 4*(size_t)t;
        const v4f* s4 = (const v4f*)scales + 3*(size_t)t;

        float pb[12], qb[16], sb[12];
        *(v4f*)&pb[0] = p4[0]; *(v4f*)&pb[4] = p4[1]; *(v4f*)&pb[8] = p4[2];
        *(v4f*)&qb[0] = q4[0]; *(v4f*)&qb[4] = q4[1];
        *(v4f*)&qb[8] = q4[2]; *(v4f*)&qb[12] = q4[3];
        *(v4f*)&sb[0] = s4[0]; *(v4f*)&sb[4] = s4[1]; *(v4f*)&sb[8] = s4[2];

        float ub[8], zb[4], cb[16];
        #pragma unroll
        for (int j = 0; j < 4; ++j) {
            project(pb[3*j+0], pb[3*j+1], pb[3*j+2],
                    qb[4*j+0], qb[4*j+1], qb[4*j+2], qb[4*j+3],
                    sb[3*j+0], sb[3*j+1], sb[3*j+2],
                    ub[2*j+0], ub[2*j+1], zb[j],
                    cb[4*j+0], cb[4*j+1], cb[4*j+2], cb[4*j+3]);
        }

        v4f* uvout = (v4f*)out + 2*(size_t)t;
        __builtin_nontemporal_store(*(v4f*)&ub[0], &uvout[0]);
        __builtin_nontemporal_store(*(v4f*)&ub[4], &uvout[1]);

        v4f* zout = (v4f*)(out + 2*(size_t)n) + t;
        __builtin_nontemporal_store(*(v4f*)&zb[0], zout);

        v4f* cout = (v4f*)(out + 3*(size_t)n) + (size_t)i0;
        #pragma unroll
        for (int j = 0; j < 4; ++j)
            __builtin_nontemporal_store(*(v4f*)&cb[4*j], &cout[j]);
    } else {
        // ---- scalar tail (also covers n % 4 != 0) ----
        for (long long i = i0; i < n && i < i0 + 4; ++i) {
            const float px = points[3*i+0], py = points[3*i+1], pz = points[3*i+2];
            const float qw = quats[4*i+0], qx = quats[4*i+1];
            const float qy = quats[4*i+2], qz_ = quats[4*i+3];
            const float sx = scales[3*i+0], sy = scales[3*i+1], sz = scales[3*i+2];
            float u, v, zc, o00, o01, o10, o11;
            project(px, py, pz, qw, qx, qy, qz_, sx, sy, sz,
                    u, v, zc, o00, o01, o10, o11);
            out[2*i+0] = u; out[2*i+1] = v;
            out[2*(size_t)n + i] = zc;
            float* cov_out = out + 3*(size_t)n + 4*i;
            cov_out[0] = o00; cov_out[1] = o01; cov_out[2] = o10; cov_out[3] = o11;
        }
    }
}

extern "C" void kernel_launch(void* const* d_in, const int* in_sizes, int n_in,
                              void* d_out, int out_size, void* d_ws, size_t ws_size,
                              hipStream_t stream) {
    const float* points = (const float*)d_in[0];
    const float* quats  = (const float*)d_in[1];
    const float* scales = (const float*)d_in[2];
    const float* E      = (const float*)d_in[3];
    const float* K      = (const float*)d_in[4];
    float* out = (float*)d_out;

    const int n = in_sizes[0] / 3;
    const int threads = (n + 3) / 4;       // 4 points per thread
    const int block = 256;
    const int grid = (threads + block - 1) / block;
    gs_project_kernel<<<grid, block, 0, stream>>>(points, quats, scales, E, K, out, n);
}

// Round 3
// 138.589 us; speedup vs baseline: 1.1584x; 1.1584x over previous
//
#include <hip/hip_runtime.h>
#include <cstdint>

typedef float v4f __attribute__((ext_vector_type(4)));

// fast reciprocal: v_rcp_f32 + 1 Newton-Raphson step (~1 ulp)
__device__ __forceinline__ float frcp(float x) {
    float r = __builtin_amdgcn_rcpf(x);
    return r * (2.0f - x * r);
}
// fast rsqrt: v_rsq_f32 + 1 Newton-Raphson step
__device__ __forceinline__ float frsq(float x) {
    float r = __builtin_amdgcn_rsqf(x);
    return r * (1.5f - 0.5f * x * r * r);
}

struct POut { float u, v, zc, o00, o01, o10, o11; };

// 4 points per thread; every bulk stream is a 16 B/lane dwordx4 access.
// All staging lives in SSA v4f values (no address-taken arrays -> no scratch).
__global__ __launch_bounds__(256) void gs_project_kernel(
    const float* __restrict__ points,   // N*3
    const float* __restrict__ quats,    // N*4
    const float* __restrict__ scales,   // N*3
    const float* __restrict__ E,        // 16 (4x4 row-major extrinsic)
    const float* __restrict__ K,        // 12 (3x4 row-major intrinsic)
    float* __restrict__ out,            // [uv: 2N][z: N][cov: 4N]
    int n)
{
    const int t = blockIdx.x * blockDim.x + threadIdx.x;
    const long long i0 = (long long)t * 4;
    if (i0 >= n) return;

    // Wave-uniform broadcast loads (stay in SGPRs).
    const float e00=E[0],  e01=E[1],  e02=E[2],  e03=E[3];
    const float e10=E[4],  e11=E[5],  e12=E[6],  e13=E[7];
    const float e20=E[8],  e21=E[9],  e22=E[10], e23=E[11];
    const float e30=E[12], e31=E[13], e32=E[14], e33=E[15];
    const float k00=K[0],  k01=K[1],  k02=K[2],  k03=K[3];
    const float k10=K[4],  k11=K[5],  k12=K[6],  k13=K[7];
    const float k20=K[8],  k21=K[9],  k22=K[10], k23=K[11];

    auto project = [&](float px, float py, float pz,
                       float qw, float qx, float qy, float qz_,
                       float sx, float sy, float sz) -> POut
    {
        const float qi = frsq(qw*qw + qx*qx + qy*qy + qz_*qz_);
        const float w = qw*qi, x = qx*qi, y = qy*qi, z = qz_*qi;

        const float r00 = 1.f - 2.f*(y*y + z*z);
        const float r01 = 2.f*(x*y - w*z);
        const float r02 = 2.f*(x*z + w*y);
        const float r10 = 2.f*(x*y + w*z);
        const float r11 = 1.f - 2.f*(x*x + z*z);
        const float r12 = 2.f*(y*z - w*x);
        const float r20 = 2.f*(x*z - w*y);
        const float r21 = 2.f*(y*z + w*x);
        const float r22 = 1.f - 2.f*(x*x + y*y);

        const float m00=r00*sx, m01=r01*sy, m02=r02*sz;
        const float m10=r10*sx, m11=r11*sy, m12=r12*sz;
        const float m20=r20*sx, m21=r21*sy, m22=r22*sz;

        const float c00 = m00*m00 + m01*m01 + m02*m02;
        const float c01 = m00*m10 + m01*m11 + m02*m12;
        const float c02 = m00*m20 + m01*m21 + m02*m22;
        const float c11 = m10*m10 + m11*m11 + m12*m12;
        const float c12 = m10*m20 + m11*m21 + m12*m22;
        const float c22 = m20*m20 + m21*m21 + m22*m22;

        const float camx = e00*px + e01*py + e02*pz + e03;
        const float camy = e10*px + e11*py + e12*pz + e13;
        const float camz = e20*px + e21*py + e22*pz + e23;
        const float camw = e30*px + e31*py + e32*pz + e33;
        const float iw = frcp(camw);
        const float cx = camx*iw, cy = camy*iw, cz = camz*iw;

        const float p0 = k00*cx + k01*cy + k02*cz + k03;
        const float p1 = k10*cx + k11*cy + k12*cz + k13;
        const float p2 = k20*cx + k21*cy + k22*cz + k23;
        const float ip2 = frcp(p2);

        const float fx = k00, fy = k11;
        const float icz = frcp(cz);
        const float j00 = fx*icz;
        const float j02 = -fx*cx*icz*icz;
        const float j11 = fy*icz;
        const float j12 = -fy*cy*icz*icz;

        // T = J @ E[:3,:3]
        const float t00 = j00*e00 + j02*e20;
        const float t01 = j00*e01 + j02*e21;
        const float t02 = j00*e02 + j02*e22;
        const float t10 = j11*e10 + j12*e20;
        const float t11 = j11*e11 + j12*e21;
        const float t12 = j11*e12 + j12*e22;

        const float a00 = t00*c00 + t01*c01 + t02*c02;
        const float a01 = t00*c01 + t01*c11 + t02*c12;
        const float a02 = t00*c02 + t01*c12 + t02*c22;
        const float a10 = t10*c00 + t11*c01 + t12*c02;
        const float a11 = t10*c01 + t11*c11 + t12*c12;
        const float a12 = t10*c02 + t11*c12 + t12*c22;

        POut o;
        o.u  = p0*ip2;
        o.v  = p1*ip2;
        o.zc = camz;                     // z_component is pre-divide cam[:,2]
        o.o00 = a00*t00 + a01*t01 + a02*t02;
        o.o01 = a00*t10 + a01*t11 + a02*t12;
        o.o10 = a10*t00 + a11*t01 + a12*t02;
        o.o11 = a10*t10 + a11*t11 + a12*t12;
        return o;
    };

    if (((n & 3) == 0) && (i0 + 3 < n)) {
        // ---- fully vectorized path: 16 B/lane loads, SSA staging only ----
        const v4f* p4 = (const v4f*)points + 3*(size_t)t;
        const v4f* q4 = (const v4f*)quats  + 4*(size_t)t;
        const v4f* s4 = (const v4f*)scales + 3*(size_t)t;

        const v4f P0 = p4[0], P1 = p4[1], P2 = p4[2];
        const v4f Q0 = q4[0], Q1 = q4[1], Q2 = q4[2], Q3 = q4[3];
        const v4f S0 = s4[0], S1 = s4[1], S2 = s4[2];

        const POut r0 = project(P0.x, P0.y, P0.z,  Q0.x, Q0.y, Q0.z, Q0.w,  S0.x, S0.y, S0.z);
        const POut r1 = project(P0.w, P1.x, P1.y,  Q1.x, Q1.y, Q1.z, Q1.w,  S0.w, S1.x, S1.y);
        const POut r2 = project(P1.z, P1.w, P2.x,  Q2.x, Q2.y, Q2.z, Q2.w,  S1.z, S1.w, S2.x);
        const POut r3 = project(P2.y, P2.z, P2.w,  Q3.x, Q3.y, Q3.z, Q3.w,  S2.y, S2.z, S2.w);

        const v4f U0 = {r0.u, r0.v, r1.u, r1.v};
        const v4f U1 = {r2.u, r2.v, r3.u, r3.v};
        const v4f Z  = {r0.zc, r1.zc, r2.zc, r3.zc};
        const v4f C0 = {r0.o00, r0.o01, r0.o10, r0.o11};
        const v4f C1 = {r1.o00, r1.o01, r1.o10, r1.o11};
        const v4f C2 = {r2.o00, r2.o01, r2.o10, r2.o11};
        const v4f C3 = {r3.o00, r3.o01, r3.o10, r3.o11};

        v4f* uvout = (v4f*)out + 2*(size_t)t;
        uvout[0] = U0;
        uvout[1] = U1;

        v4f* zout = (v4f*)(out + 2*(size_t)n) + t;
        zout[0] = Z;

        v4f* cout = (v4f*)(out + 3*(size_t)n) + (size_t)i0;
        cout[0] = C0; cout[1] = C1; cout[2] = C2; cout[3] = C3;
    } else {
        // ---- scalar tail (n % 4 != 0) ----
        for (long long i = i0; i < n && i < i0 + 4; ++i) {
            const POut r = project(points[3*i+0], points[3*i+1], points[3*i+2],
                                   quats[4*i+0], quats[4*i+1], quats[4*i+2], quats[4*i+3],
                                   scales[3*i+0], scales[3*i+1], scales[3*i+2]);
            out[2*i+0] = r.u; out[2*i+1] = r.v;
            out[2*(size_t)n + i] = r.zc;
            float* cov_out = out + 3*(size_t)n + 4*i;
            cov_out[0] = r.o00; cov_out[1] = r.o01; cov_out[2] = r.o10; cov_out[3] = r.o11;
        }
    }
}

extern "C" void kernel_launch(void* const* d_in, const int* in_sizes, int n_in,
                              void* d_out, int out_size, void* d_ws, size_t ws_size,
                              hipStream_t stream) {
    const float* points = (const float*)d_in[0];
    const float* quats  = (const float*)d_in[1];
    const float* scales = (const float*)d_in[2];
    const float* E      = (const float*)d_in[3];
    const float* K      = (const float*)d_in[4];
    float* out = (float*)d_out;

    const int n = in_sizes[0] / 3;
    const int threads = (n + 3) / 4;       // 4 points per thread
    const int block = 256;
    const int grid = (threads + block - 1) / block;
    gs_project_kernel<<<grid, block, 0, stream>>>(points, quats, scales, E, K, out, n);
}

// Round 4
// 126.316 us; speedup vs baseline: 1.2710x; 1.0972x over previous
//
#include <hip/hip_runtime.h>
#include <cstdint>

typedef float v4f __attribute__((ext_vector_type(4)));
typedef float v2f __attribute__((ext_vector_type(2)));

// fast reciprocal: v_rcp_f32 + 1 Newton-Raphson step (~1 ulp)
__device__ __forceinline__ float frcp(float x) {
    float r = __builtin_amdgcn_rcpf(x);
    return r * (2.0f - x * r);
}
// fast rsqrt: v_rsq_f32 + 1 Newton-Raphson step
__device__ __forceinline__ float frsq(float x) {
    float r = __builtin_amdgcn_rsqf(x);
    return r * (1.5f - 0.5f * x * r * r);
}

struct POut { float u, v, zc, o00, o01, o10, o11; };

// Wave-strided assignment: wave owns 256 consecutive points, lane l handles
// {base+l, base+64+l, base+128+l, base+192+l}. quats/cov/uv/z accesses are all
// lane-contiguous (fully coalesced, direct). points/scales (3 floats/point)
// are staged through LDS with coalesced v4f loads; compute-phase ds_read_b32
// at word-stride 3 is bank-conflict-free (gcd(3,32)=1).
__global__ __launch_bounds__(256) void gs_project_kernel(
    const float* __restrict__ points,   // N*3
    const float* __restrict__ quats,    // N*4
    const float* __restrict__ scales,   // N*3
    const float* __restrict__ E,        // 16 (4x4 row-major extrinsic)
    const float* __restrict__ K,        // 12 (3x4 row-major intrinsic)
    float* __restrict__ out,            // [uv: 2N][z: N][cov: 4N]
    int n)
{
    const int tid  = threadIdx.x;
    const int lane = tid & 63;
    const int wv   = tid >> 6;
    const long long blockBase = (long long)blockIdx.x * 1024;

    __shared__ float lds_p[3072];   // 1024 points x 3
    __shared__ float lds_s[3072];   // 1024 points x 3

    // Wave-uniform broadcast loads (stay in SGPRs).
    const float e00=E[0],  e01=E[1],  e02=E[2],  e03=E[3];
    const float e10=E[4],  e11=E[5],  e12=E[6],  e13=E[7];
    const float e20=E[8],  e21=E[9],  e22=E[10], e23=E[11];
    const float e30=E[12], e31=E[13], e32=E[14], e33=E[15];
    const float k00=K[0],  k01=K[1],  k02=K[2],  k03=K[3];
    const float k10=K[4],  k11=K[5],  k12=K[6],  k13=K[7];
    const float k20=K[8],  k21=K[9],  k22=K[10], k23=K[11];

    auto project = [&](float px, float py, float pz,
                       float qw, float qx, float qy, float qz_,
                       float sx, float sy, float sz) -> POut
    {
        const float qi = frsq(qw*qw + qx*qx + qy*qy + qz_*qz_);
        const float w = qw*qi, x = qx*qi, y = qy*qi, z = qz_*qi;

        const float r00 = 1.f - 2.f*(y*y + z*z);
        const float r01 = 2.f*(x*y - w*z);
        const float r02 = 2.f*(x*z + w*y);
        const float r10 = 2.f*(x*y + w*z);
        const float r11 = 1.f - 2.f*(x*x + z*z);
        const float r12 = 2.f*(y*z - w*x);
        const float r20 = 2.f*(x*z - w*y);
        const float r21 = 2.f*(y*z + w*x);
        const float r22 = 1.f - 2.f*(x*x + y*y);

        const float m00=r00*sx, m01=r01*sy, m02=r02*sz;
        const float m10=r10*sx, m11=r11*sy, m12=r12*sz;
        const float m20=r20*sx, m21=r21*sy, m22=r22*sz;

        const float c00 = m00*m00 + m01*m01 + m02*m02;
        const float c01 = m00*m10 + m01*m11 + m02*m12;
        const float c02 = m00*m20 + m01*m21 + m02*m22;
        const float c11 = m10*m10 + m11*m11 + m12*m12;
        const float c12 = m10*m20 + m11*m21 + m12*m22;
        const float c22 = m20*m20 + m21*m21 + m22*m22;

        const float camx = e00*px + e01*py + e02*pz + e03;
        const float camy = e10*px + e11*py + e12*pz + e13;
        const float camz = e20*px + e21*py + e22*pz + e23;
        const float camw = e30*px + e31*py + e32*pz + e33;
        const float iw = frcp(camw);
        const float cx = camx*iw, cy = camy*iw, cz = camz*iw;

        const float p0 = k00*cx + k01*cy + k02*cz + k03;
        const float p1 = k10*cx + k11*cy + k12*cz + k13;
        const float p2 = k20*cx + k21*cy + k22*cz + k23;
        const float ip2 = frcp(p2);

        const float fx = k00, fy = k11;
        const float icz = frcp(cz);
        const float j00 = fx*icz;
        const float j02 = -fx*cx*icz*icz;
        const float j11 = fy*icz;
        const float j12 = -fy*cy*icz*icz;

        // T = J @ E[:3,:3]
        const float t00 = j00*e00 + j02*e20;
        const float t01 = j00*e01 + j02*e21;
        const float t02 = j00*e02 + j02*e22;
        const float t10 = j11*e10 + j12*e20;
        const float t11 = j11*e11 + j12*e21;
        const float t12 = j11*e12 + j12*e22;

        const float a00 = t00*c00 + t01*c01 + t02*c02;
        const float a01 = t00*c01 + t01*c11 + t02*c12;
        const float a02 = t00*c02 + t01*c12 + t02*c22;
        const float a10 = t10*c00 + t11*c01 + t12*c02;
        const float a11 = t10*c01 + t11*c11 + t12*c12;
        const float a12 = t10*c02 + t11*c12 + t12*c22;

        POut o;
        o.u  = p0*ip2;
        o.v  = p1*ip2;
        o.zc = camz;                     // z_component is pre-divide cam[:,2]
        o.o00 = a00*t00 + a01*t01 + a02*t02;
        o.o01 = a00*t10 + a01*t11 + a02*t12;
        o.o10 = a10*t00 + a11*t01 + a12*t02;
        o.o11 = a10*t10 + a11*t11 + a12*t12;
        return o;
    };

    if (blockBase + 1024 <= n) {
        // ---- fast path: full block of 1024 points ----
        // Stage points & scales: lane-contiguous v4f loads -> LDS.
        const v4f* gp = (const v4f*)points + (size_t)blockIdx.x * 768;
        const v4f* gs = (const v4f*)scales + (size_t)blockIdx.x * 768;
        v4f* lp = (v4f*)lds_p;
        v4f* ls = (v4f*)lds_s;
        #pragma unroll
        for (int m = 0; m < 3; ++m) {
            lp[tid + 256*m] = gp[tid + 256*m];
            ls[tid + 256*m] = gs[tid + 256*m];
        }
        __syncthreads();

        const long long waveBase = blockBase + 256*wv;
        const int lbase = 256*wv;

        const v4f* gq = (const v4f*)quats;
        v2f* uvout = (v2f*)out;
        float* zout = out + 2*(size_t)n;
        v4f* cout = (v4f*)(out + 3*(size_t)n);

        #pragma unroll
        for (int k = 0; k < 4; ++k) {
            const long long p = waveBase + 64*k + lane;   // global point idx
            const int pl = 3*(lbase + 64*k + lane);       // LDS word idx

            const v4f q = gq[p];                          // coalesced 16 B/lane
            const float px = lds_p[pl+0], py = lds_p[pl+1], pz = lds_p[pl+2];
            const float sx = lds_s[pl+0], sy = lds_s[pl+1], sz = lds_s[pl+2];

            const POut r = project(px, py, pz, q.x, q.y, q.z, q.w, sx, sy, sz);

            uvout[p] = (v2f){r.u, r.v};                   // coalesced 8 B/lane
            zout[p]  = r.zc;                              // coalesced 4 B/lane
            cout[p]  = (v4f){r.o00, r.o01, r.o10, r.o11}; // coalesced 16 B/lane
        }
    } else {
        // ---- tail block: scalar per point ----
        for (long long i = blockBase + tid; i < n; i += 256) {
            const POut r = project(points[3*i+0], points[3*i+1], points[3*i+2],
                                   quats[4*i+0], quats[4*i+1], quats[4*i+2], quats[4*i+3],
                                   scales[3*i+0], scales[3*i+1], scales[3*i+2]);
            out[2*i+0] = r.u; out[2*i+1] = r.v;
            out[2*(size_t)n + i] = r.zc;
            float* cov_out = out + 3*(size_t)n + 4*i;
            cov_out[0] = r.o00; cov_out[1] = r.o01; cov_out[2] = r.o10; cov_out[3] = r.o11;
        }
    }
}

extern "C" void kernel_launch(void* const* d_in, const int* in_sizes, int n_in,
                              void* d_out, int out_size, void* d_ws, size_t ws_size,
                              hipStream_t stream) {
    const float* points = (const float*)d_in[0];
    const float* quats  = (const float*)d_in[1];
    const float* scales = (const float*)d_in[2];
    const float* E      = (const float*)d_in[3];
    const float* K      = (const float*)d_in[4];
    float* out = (float*)d_out;

    const int n = in_sizes[0] / 3;
    const int block = 256;                      // 4 waves, 1024 points/block
    const int grid = (n + 1023) / 1024;
    gs_project_kernel<<<grid, block, 0, stream>>>(points, quats, scales, E, K, out, n);
}